// Round 6
// baseline (206.638 us; speedup 1.0000x reference)
//
#include <hip/hip_runtime.h>

#define N_NODES 50000
#define N_EDGES 800000
// D_S=64, D_R=16, D_E=64, D_X=16, D_P=64, NUM_CLASSES=10
// W_r: [144,64]; W_o: [144,64]; W_s: [64,10] (all row-major)
//
// Linear refactor: scores[n] = O[n]@A_O + X[n]@A_X + deg_n*(O[n]@A_dO + c0)
//                              + c1 + sum_{e->n} (O[s_e]@A_S + R_a[e]@A_R)
// with Wc = W_o@W_s [144,10], Wc2 = Wc[80:144],
//   A_O = Wc[0:64], A_X = Wc[64:80], A_S = W_r[0:64]@Wc2,
//   A_R = W_r[128:144]@Wc2, A_dO = W_r[64:128]@Wc2,
//   c0 = b_r@Wc2, c1 = b_o@W_s + b_s.
//
// A-table layout in ws: [226][16] f32 (cols 10..15 zeroed):
//   rows 0..63 A_O | 64..79 A_X | 80..143 A_S | 144..159 A_R |
//   160..223 A_dO | 224 c0 | 225 c1

// ---------------------------------------------------------------------------
// Workspace layout (bytes) — WS_NEED = 0x0D0000 + 19,200,000 = 20.1 MB
// ---------------------------------------------------------------------------
#define WS_A       ((size_t)0x000000)   // 226*16*4 = 14,464 B
#define WS_COUNT   ((size_t)0x010000)   // 50000 i32 = 200,000 B
#define WS_CURSOR  (WS_COUNT + (size_t)200000)  // 1 u32 (memset with count)
#define WS_OFF     ((size_t)0x050000)   // 50000 i32
#define WS_CUR     ((size_t)0x090000)   // 50000 i32
#define WS_W       ((size_t)0x0D0000)   // 800000*6 u32 (bf16 pairs) = 19.2 MB

__device__ __forceinline__ unsigned int f32_to_bf16_rne(float f) {
    unsigned int x = __float_as_uint(f);
    return (x + 0x7fffu + ((x >> 16) & 1u)) >> 16;
}

// ---------------------------------------------------------------------------
// Precompute folded weight table A — 10 blocks, each with redundant Wc2 in LDS
// ---------------------------------------------------------------------------
__global__ __launch_bounds__(256) void precompute_A(
    const float* __restrict__ W_r, const float* __restrict__ b_r,
    const float* __restrict__ W_o, const float* __restrict__ b_o,
    const float* __restrict__ W_s, const float* __restrict__ b_s,
    float* __restrict__ A)
{
    __shared__ float Wc2[640];  // Wc rows 80..143 (64 x 10)
    const int t = threadIdx.x;

    // every block computes Wc2 redundantly (3 entries/thread, 64 FMA each)
    for (int idx = t; idx < 640; idx += 256) {
        const int row = 80 + idx / 10, c = idx % 10;
        float acc = 0.f;
        for (int j = 0; j < 64; ++j)
            acc = fmaf(W_o[row * 64 + j], W_s[j * 10 + c], acc);
        Wc2[idx] = acc;
    }
    __syncthreads();

    // work items:
    //  [0,1356)      zero pads (226 rows x cols 10..15)
    //  [1356,2156)   phase1: A_O/A_X rows 0..79 (800)
    //  [2156,3596)   A_S / A_R / A_dO (144 x 10)
    //  [3596,3606)   c0
    //  [3606,3616)   c1
    for (int g = blockIdx.x * 256 + t; g < 3616; g += gridDim.x * 256) {
        if (g < 1356) {
            const int row = g / 6, c = 10 + g % 6;
            A[row * 16 + c] = 0.f;
        } else if (g < 2156) {
            const int i = g - 1356, row = i / 10, c = i % 10;
            float acc = 0.f;
            for (int j = 0; j < 64; ++j)
                acc = fmaf(W_o[row * 64 + j], W_s[j * 10 + c], acc);
            A[row * 16 + c] = acc;
        } else if (g < 3596) {
            const int i = g - 2156, k = i / 10, c = i % 10;
            const int wrow = (k < 64) ? k : (k < 80 ? 128 + (k - 64) : 64 + (k - 80));
            const int arow = (k < 64) ? 80 + k : (k < 80 ? 144 + (k - 64) : 160 + (k - 80));
            const float* src = W_r + (size_t)wrow * 64;
            float acc = 0.f;
            for (int m = 0; m < 64; ++m)
                acc = fmaf(src[m], Wc2[m * 10 + c], acc);
            A[arow * 16 + c] = acc;
        } else if (g < 3606) {
            const int c = g - 3596;
            float acc = 0.f;
            for (int m = 0; m < 64; ++m)
                acc = fmaf(b_r[m], Wc2[m * 10 + c], acc);
            A[224 * 16 + c] = acc;
        } else {
            const int c = g - 3606;
            float acc = b_s[c];
            for (int j = 0; j < 64; ++j)
                acc = fmaf(b_o[j], W_s[j * 10 + c], acc);
            A[225 * 16 + c] = acc;
        }
    }
}

// ---------------------------------------------------------------------------
// Receiver histogram, 4 edges/thread (int4 loads)
// ---------------------------------------------------------------------------
__global__ __launch_bounds__(256) void count_kernel(
    const int* __restrict__ receivers, int* __restrict__ count)
{
    const int t = blockIdx.x * 256 + threadIdx.x;
    if (t * 4 >= N_EDGES) return;
    const int4 r4 = reinterpret_cast<const int4*>(receivers)[t];
    atomicAdd(count + r4.x, 1);
    atomicAdd(count + r4.y, 1);
    atomicAdd(count + r4.z, 1);
    atomicAdd(count + r4.w, 1);
}

// ---------------------------------------------------------------------------
// Segment allocation: off[n] = atomicAdd(cursor, count[n]) (order-free CSR)
// ---------------------------------------------------------------------------
__global__ __launch_bounds__(256) void alloc_kernel(
    const int* __restrict__ count, unsigned int* __restrict__ cursor,
    int* __restrict__ off, int* __restrict__ cur)
{
    const int n = blockIdx.x * 256 + threadIdx.x;
    if (n >= N_NODES) return;
    const int c = count[n];
    const int pos = (int)atomicAdd(cursor, (unsigned int)c);
    off[n] = pos;
    cur[n] = pos;
}

// ---------------------------------------------------------------------------
// Per-edge w_e = O[s_e]@A_S + R_a[e]@A_R, bf16-packed, written directly to
// receiver-sorted slot. 2 edges/thread: both O-rows, R_a-rows, and slot
// atomics issued up front so latency overlaps the interleaved FMA chains.
// ---------------------------------------------------------------------------
__global__ __launch_bounds__(256) void edge_w_kernel(
    const float* __restrict__ O, const float* __restrict__ R_a,
    const int* __restrict__ senders, const int* __restrict__ receivers,
    const float* __restrict__ A,
    int* __restrict__ cur,
    unsigned int* __restrict__ wsorted)   // [E][6] dwords, 24 B stride
{
    const int e0 = (blockIdx.x * 256 + threadIdx.x) * 2;
    if (e0 >= N_EDGES) return;  // N_EDGES even -> e0+1 also valid

    const int2 s2 = *reinterpret_cast<const int2*>(senders + e0);
    const int2 r2 = *reinterpret_cast<const int2*>(receivers + e0);

    // claim sorted slots early — atomic latency hides under the FMA work
    const int pos0 = atomicAdd(cur + r2.x, 1);
    const int pos1 = atomicAdd(cur + r2.y, 1);

    const float4* O0 = reinterpret_cast<const float4*>(O + (size_t)s2.x * 64);
    const float4* O1 = reinterpret_cast<const float4*>(O + (size_t)s2.y * 64);
    const float4* Ra = reinterpret_cast<const float4*>(R_a + (size_t)e0 * 16);

    float a0[10], a1[10];
#pragma unroll
    for (int c = 0; c < 10; ++c) { a0[c] = 0.f; a1[c] = 0.f; }

    // O[s] @ A_S (A rows 80..143), both edges interleaved
#pragma unroll
    for (int kc = 0; kc < 16; ++kc) {
        const float4 b4 = O0[kc];
        const float4 c4 = O1[kc];
        const float* A0 = A + (size_t)(80 + kc * 4) * 16;
#pragma unroll
        for (int c = 0; c < 10; ++c) {
            a0[c] = fmaf(b4.x, A0[c], a0[c]);
            a1[c] = fmaf(c4.x, A0[c], a1[c]);
        }
#pragma unroll
        for (int c = 0; c < 10; ++c) {
            a0[c] = fmaf(b4.y, A0[16 + c], a0[c]);
            a1[c] = fmaf(c4.y, A0[16 + c], a1[c]);
        }
#pragma unroll
        for (int c = 0; c < 10; ++c) {
            a0[c] = fmaf(b4.z, A0[32 + c], a0[c]);
            a1[c] = fmaf(c4.z, A0[32 + c], a1[c]);
        }
#pragma unroll
        for (int c = 0; c < 10; ++c) {
            a0[c] = fmaf(b4.w, A0[48 + c], a0[c]);
            a1[c] = fmaf(c4.w, A0[48 + c], a1[c]);
        }
    }
    // R_a[e] @ A_R (A rows 144..159), both edges (R_a rows contiguous: 8 x float4)
#pragma unroll
    for (int kc = 0; kc < 4; ++kc) {
        const float4 b4 = Ra[kc];
        const float4 c4 = Ra[4 + kc];
        const float* A0 = A + (size_t)(144 + kc * 4) * 16;
#pragma unroll
        for (int c = 0; c < 10; ++c) {
            a0[c] = fmaf(b4.x, A0[c], a0[c]);
            a1[c] = fmaf(c4.x, A0[c], a1[c]);
        }
#pragma unroll
        for (int c = 0; c < 10; ++c) {
            a0[c] = fmaf(b4.y, A0[16 + c], a0[c]);
            a1[c] = fmaf(c4.y, A0[16 + c], a1[c]);
        }
#pragma unroll
        for (int c = 0; c < 10; ++c) {
            a0[c] = fmaf(b4.z, A0[32 + c], a0[c]);
            a1[c] = fmaf(c4.z, A0[32 + c], a1[c]);
        }
#pragma unroll
        for (int c = 0; c < 10; ++c) {
            a0[c] = fmaf(b4.w, A0[48 + c], a0[c]);
            a1[c] = fmaf(c4.w, A0[48 + c], a1[c]);
        }
    }

    // pack + store (5 dwords each, 24 B stride -> 8-aligned uint2 pairs)
    {
        unsigned int* wp = wsorted + (size_t)pos0 * 6;
        uint2 u01, u23;
        u01.x = f32_to_bf16_rne(a0[0]) | (f32_to_bf16_rne(a0[1]) << 16);
        u01.y = f32_to_bf16_rne(a0[2]) | (f32_to_bf16_rne(a0[3]) << 16);
        u23.x = f32_to_bf16_rne(a0[4]) | (f32_to_bf16_rne(a0[5]) << 16);
        u23.y = f32_to_bf16_rne(a0[6]) | (f32_to_bf16_rne(a0[7]) << 16);
        *reinterpret_cast<uint2*>(wp) = u01;
        *reinterpret_cast<uint2*>(wp + 2) = u23;
        wp[4] = f32_to_bf16_rne(a0[8]) | (f32_to_bf16_rne(a0[9]) << 16);
    }
    {
        unsigned int* wp = wsorted + (size_t)pos1 * 6;
        uint2 u01, u23;
        u01.x = f32_to_bf16_rne(a1[0]) | (f32_to_bf16_rne(a1[1]) << 16);
        u01.y = f32_to_bf16_rne(a1[2]) | (f32_to_bf16_rne(a1[3]) << 16);
        u23.x = f32_to_bf16_rne(a1[4]) | (f32_to_bf16_rne(a1[5]) << 16);
        u23.y = f32_to_bf16_rne(a1[6]) | (f32_to_bf16_rne(a1[7]) << 16);
        *reinterpret_cast<uint2*>(wp) = u01;
        *reinterpret_cast<uint2*>(wp + 2) = u23;
        wp[4] = f32_to_bf16_rne(a1[8]) | (f32_to_bf16_rne(a1[9]) << 16);
    }
}

// ---------------------------------------------------------------------------
// Node scores: thread = (node, class-slot c<16); contiguous w gather; softmax.
// ---------------------------------------------------------------------------
__global__ __launch_bounds__(256) void node_score_kernel(
    const float* __restrict__ O, const float* __restrict__ X,
    const int* __restrict__ off, const int* __restrict__ count,
    const unsigned int* __restrict__ w,   // [E][6] dwords, receiver-sorted
    const float* __restrict__ A,
    float* __restrict__ out)
{
    const int tid = blockIdx.x * 256 + threadIdx.x;
    const int n = tid >> 4;
    const int c = tid & 15;
    if (n >= N_NODES) return;

    float s1 = 0.f, s2 = 0.f;
    // O part: A_O (rows 0..63) and A_dO (rows 160..223)
#pragma unroll 8
    for (int k = 0; k < 64; ++k) {
        const float o = O[(size_t)n * 64 + k];
        s1 = fmaf(o, A[(size_t)k * 16 + c], s1);
        s2 = fmaf(o, A[(size_t)(160 + k) * 16 + c], s2);
    }
    // X part: A_X (rows 64..79)
#pragma unroll
    for (int k = 0; k < 16; ++k) {
        const float x = X[(size_t)n * 16 + k];
        s1 = fmaf(x, A[(size_t)(64 + k) * 16 + c], s1);
    }

    const int beg = off[n];
    const int dge = count[n];
    const int end = beg + dge;
    const float dg = (float)dge;
    float sc = s1 + dg * s2 + dg * A[224 * 16 + c] + A[225 * 16 + c];

    // sum bf16 w_e over this node's contiguous segment
    const int half = (c < 10) ? (c >> 1) : 0;
    const int sh = (c & 1) * 16;
    int i = beg;
    for (; i + 3 < end; i += 4) {
        const unsigned int u0 = w[(size_t)(i + 0) * 6 + half];
        const unsigned int u1 = w[(size_t)(i + 1) * 6 + half];
        const unsigned int u2 = w[(size_t)(i + 2) * 6 + half];
        const unsigned int u3 = w[(size_t)(i + 3) * 6 + half];
        sc += __uint_as_float((u0 >> sh) << 16);
        sc += __uint_as_float((u1 >> sh) << 16);
        sc += __uint_as_float((u2 >> sh) << 16);
        sc += __uint_as_float((u3 >> sh) << 16);
    }
    for (; i < end; ++i) {
        const unsigned int u = w[(size_t)i * 6 + half];
        sc += __uint_as_float((u >> sh) << 16);
    }

    // softmax over the 10 active lanes of this 16-lane group
    float m = (c < 10) ? sc : -3.0e38f;
#pragma unroll
    for (int d = 1; d < 16; d <<= 1) m = fmaxf(m, __shfl_xor(m, d, 16));
    const float ex = (c < 10) ? __expf(sc - m) : 0.f;
    float sum = ex;
#pragma unroll
    for (int d = 1; d < 16; d <<= 1) sum += __shfl_xor(sum, d, 16);
    if (c < 10) out[(size_t)n * 10 + c] = ex / sum;
}

extern "C" void kernel_launch(void* const* d_in, const int* in_sizes, int n_in,
                              void* d_out, int out_size, void* d_ws, size_t ws_size,
                              hipStream_t stream)
{
    const float* O    = (const float*)d_in[0];
    const float* X    = (const float*)d_in[1];
    const float* R_a  = (const float*)d_in[2];
    const int* senders   = (const int*)d_in[3];
    const int* receivers = (const int*)d_in[4];
    const float* W_r  = (const float*)d_in[5];
    const float* b_r  = (const float*)d_in[6];
    const float* W_o  = (const float*)d_in[7];
    const float* b_o  = (const float*)d_in[8];
    const float* W_s  = (const float*)d_in[9];
    const float* b_s  = (const float*)d_in[10];
    float* out = (float*)d_out;
    char* ws = (char*)d_ws;

    float* A      = (float*)(ws + WS_A);
    int* count    = (int*)(ws + WS_COUNT);
    unsigned int* cursor = (unsigned int*)(ws + WS_CURSOR);
    int* off      = (int*)(ws + WS_OFF);
    int* cur      = (int*)(ws + WS_CUR);
    unsigned int* w = (unsigned int*)(ws + WS_W);

    // zero count histogram + cursor (adjacent) in one memset
    hipMemsetAsync(count, 0, (size_t)200004, stream);

    precompute_A<<<10, 256, 0, stream>>>(W_r, b_r, W_o, b_o, W_s, b_s, A);

    count_kernel<<<(N_EDGES / 4 + 255) / 256, 256, 0, stream>>>(receivers, count);

    alloc_kernel<<<(N_NODES + 255) / 256, 256, 0, stream>>>(count, cursor, off, cur);

    edge_w_kernel<<<(N_EDGES / 2 + 255) / 256, 256, 0, stream>>>(
        O, R_a, senders, receivers, A, cur, w);

    node_score_kernel<<<(N_NODES * 16 + 255) / 256, 256, 0, stream>>>(
        O, X, off, count, w, A, out);
}

// Round 7
// 174.884 us; speedup vs baseline: 1.1816x; 1.1816x over previous
//
#include <hip/hip_runtime.h>

#define N_NODES 50000
#define N_EDGES 800000
// D_S=64, D_R=16, D_E=64, D_X=16, D_P=64, NUM_CLASSES=10
// W_r: [144,64]; W_o: [144,64]; W_s: [64,10] (all row-major)
//
// Linear refactor: scores[n] = u0[n] + deg_n*u1[n] + sum_{e->n} w_e
//   w_e  = u_s[s_e] + R_a[e]@A_R
//   u_s[n] = O[n]@A_S                      (per-node, NOT per-edge!)
//   u0[n]  = O[n]@A_O + X[n]@A_X + c1
//   u1[n]  = O[n]@A_dO + c0
// with Wc = W_o@W_s [144,10], Wc2 = Wc[80:144],
//   A_O = Wc[0:64], A_X = Wc[64:80], A_S = W_r[0:64]@Wc2,
//   A_R = W_r[128:144]@Wc2, A_dO = W_r[64:128]@Wc2,
//   c0 = b_r@Wc2, c1 = b_o@W_s + b_s.
//
// A-table layout in ws: [226][16] f32 (cols 10..15 zeroed):
//   rows 0..63 A_O | 64..79 A_X | 80..143 A_S | 144..159 A_R |
//   160..223 A_dO | 224 c0 | 225 c1

// ---------------------------------------------------------------------------
// Workspace layout (bytes) — total 23,340,032 B = 23.3 MB < 26.4 MB (proven)
// ---------------------------------------------------------------------------
#define WS_A       ((size_t)0x000000)   // 226*16*4 = 14,464 B
#define WS_COUNT   ((size_t)0x010000)   // 50000 i32 = 200,000 B
#define WS_CURSOR  (WS_COUNT + (size_t)200000)  // 1 u32 (memset with count)
#define WS_OFF     ((size_t)0x050000)   // 50000 i32
#define WS_CUR     ((size_t)0x090000)   // 50000 i32
#define WS_US      ((size_t)0x0D0000)   // 50000*12 f32 = 2.4 MB (rows 48B, f4-aligned)
#define WS_U01     ((size_t)0x320000)   // 50000*20 f32 = 4.0 MB (u0 cols 0..9, u1 cols 10..19)
#define WS_W       ((size_t)0x700000)   // 800000*5 u32 (bf16 pairs) = 16 MB

__device__ __forceinline__ unsigned int f32_to_bf16_rne(float f) {
    unsigned int x = __float_as_uint(f);
    return (x + 0x7fffu + ((x >> 16) & 1u)) >> 16;
}

// ---------------------------------------------------------------------------
// Precompute folded weight table A — 10 blocks, each with redundant Wc2 in LDS
// ---------------------------------------------------------------------------
__global__ __launch_bounds__(256) void precompute_A(
    const float* __restrict__ W_r, const float* __restrict__ b_r,
    const float* __restrict__ W_o, const float* __restrict__ b_o,
    const float* __restrict__ W_s, const float* __restrict__ b_s,
    float* __restrict__ A)
{
    __shared__ float Wc2[640];  // Wc rows 80..143 (64 x 10)
    const int t = threadIdx.x;

    for (int idx = t; idx < 640; idx += 256) {
        const int row = 80 + idx / 10, c = idx % 10;
        float acc = 0.f;
        for (int j = 0; j < 64; ++j)
            acc = fmaf(W_o[row * 64 + j], W_s[j * 10 + c], acc);
        Wc2[idx] = acc;
    }
    __syncthreads();

    // work items:
    //  [0,1356)      zero pads (226 rows x cols 10..15)
    //  [1356,2156)   A_O/A_X rows 0..79 (800)
    //  [2156,3596)   A_S / A_R / A_dO (144 x 10)
    //  [3596,3606)   c0
    //  [3606,3616)   c1
    for (int g = blockIdx.x * 256 + t; g < 3616; g += gridDim.x * 256) {
        if (g < 1356) {
            const int row = g / 6, c = 10 + g % 6;
            A[row * 16 + c] = 0.f;
        } else if (g < 2156) {
            const int i = g - 1356, row = i / 10, c = i % 10;
            float acc = 0.f;
            for (int j = 0; j < 64; ++j)
                acc = fmaf(W_o[row * 64 + j], W_s[j * 10 + c], acc);
            A[row * 16 + c] = acc;
        } else if (g < 3596) {
            const int i = g - 2156, k = i / 10, c = i % 10;
            const int wrow = (k < 64) ? k : (k < 80 ? 128 + (k - 64) : 64 + (k - 80));
            const int arow = (k < 64) ? 80 + k : (k < 80 ? 144 + (k - 64) : 160 + (k - 80));
            const float* src = W_r + (size_t)wrow * 64;
            float acc = 0.f;
            for (int m = 0; m < 64; ++m)
                acc = fmaf(src[m], Wc2[m * 10 + c], acc);
            A[arow * 16 + c] = acc;
        } else if (g < 3606) {
            const int c = g - 3596;
            float acc = 0.f;
            for (int m = 0; m < 64; ++m)
                acc = fmaf(b_r[m], Wc2[m * 10 + c], acc);
            A[224 * 16 + c] = acc;
        } else {
            const int c = g - 3606;
            float acc = b_s[c];
            for (int j = 0; j < 64; ++j)
                acc = fmaf(b_o[j], W_s[j * 10 + c], acc);
            A[225 * 16 + c] = acc;
        }
    }
}

// ---------------------------------------------------------------------------
// Per-node 10-vectors: u_s = O@A_S; u0 = O@A_O + X@A_X + c1; u1 = O@A_dO + c0
// Thread = (node, class): tid = n*10 + c, no idle lanes, no cross-lane ops.
// ---------------------------------------------------------------------------
__global__ __launch_bounds__(256) void node_u_kernel(
    const float* __restrict__ O, const float* __restrict__ X,
    const float* __restrict__ A,
    float* __restrict__ us, float* __restrict__ u01)
{
    const int tid = blockIdx.x * 256 + threadIdx.x;
    if (tid >= N_NODES * 10) return;
    const int n = tid / 10;
    const int c = tid - n * 10;

    float vs = 0.f, v0 = 0.f, v1 = 0.f;
    const float* Orow = O + (size_t)n * 64;
#pragma unroll 8
    for (int k = 0; k < 64; ++k) {
        const float o = Orow[k];
        vs = fmaf(o, A[(size_t)(80 + k) * 16 + c], vs);
        v0 = fmaf(o, A[(size_t)k * 16 + c], v0);
        v1 = fmaf(o, A[(size_t)(160 + k) * 16 + c], v1);
    }
    const float* Xrow = X + (size_t)n * 16;
#pragma unroll
    for (int k = 0; k < 16; ++k)
        v0 = fmaf(Xrow[k], A[(size_t)(64 + k) * 16 + c], v0);

    us[(size_t)n * 12 + c] = vs;
    u01[(size_t)n * 20 + c]      = v0 + A[225 * 16 + c];  // + c1
    u01[(size_t)n * 20 + 10 + c] = v1 + A[224 * 16 + c];  // + c0
}

// ---------------------------------------------------------------------------
// Receiver histogram, 4 edges/thread (int4 loads)
// ---------------------------------------------------------------------------
__global__ __launch_bounds__(256) void count_kernel(
    const int* __restrict__ receivers, int* __restrict__ count)
{
    const int t = blockIdx.x * 256 + threadIdx.x;
    if (t * 4 >= N_EDGES) return;
    const int4 r4 = reinterpret_cast<const int4*>(receivers)[t];
    atomicAdd(count + r4.x, 1);
    atomicAdd(count + r4.y, 1);
    atomicAdd(count + r4.z, 1);
    atomicAdd(count + r4.w, 1);
}

// ---------------------------------------------------------------------------
// Segment allocation: off[n] = atomicAdd(cursor, count[n]) (order-free CSR)
// ---------------------------------------------------------------------------
__global__ __launch_bounds__(256) void alloc_kernel(
    const int* __restrict__ count, unsigned int* __restrict__ cursor,
    int* __restrict__ off, int* __restrict__ cur)
{
    const int n = blockIdx.x * 256 + threadIdx.x;
    if (n >= N_NODES) return;
    const int c = count[n];
    const int pos = (int)atomicAdd(cursor, (unsigned int)c);
    off[n] = pos;
    cur[n] = pos;
}

// ---------------------------------------------------------------------------
// Per-edge w_e = u_s[s_e] + R_a[e]@A_R (bf16-packed, stride 5 dwords),
// written directly into receiver-sorted slot. 1 edge/thread — small gather
// footprint (48 B from 2.4 MB L2-resident u_s).
// ---------------------------------------------------------------------------
__global__ __launch_bounds__(256) void edge_w_kernel(
    const float* __restrict__ R_a,
    const int* __restrict__ senders, const int* __restrict__ receivers,
    const float* __restrict__ us, const float* __restrict__ A,
    int* __restrict__ cur,
    unsigned int* __restrict__ wsorted)   // [E][5] dwords, 20 B stride
{
    const int e = blockIdx.x * blockDim.x + threadIdx.x;
    if (e >= N_EDGES) return;
    const int s = senders[e];
    const int r = receivers[e];

    // claim sorted slot early — atomic latency hides under the FMA work
    const int pos = atomicAdd(cur + r, 1);

    // u_s[s]: 48 B (3 x float4, cols 10,11 are pad)
    const float4* U = reinterpret_cast<const float4*>(us + (size_t)s * 12);
    const float4 ua = U[0];
    const float4 ub = U[1];
    const float4 uc = U[2];
    float a[10] = {ua.x, ua.y, ua.z, ua.w, ub.x, ub.y, ub.z, ub.w, uc.x, uc.y};

    // R_a[e] @ A_R (A rows 144..159)
    const float4* Rv = reinterpret_cast<const float4*>(R_a + (size_t)e * 16);
#pragma unroll
    for (int kc = 0; kc < 4; ++kc) {
        const float4 b4 = Rv[kc];
        const float* A0 = A + (size_t)(144 + kc * 4) * 16;
#pragma unroll
        for (int c = 0; c < 10; ++c) a[c] = fmaf(b4.x, A0[c], a[c]);
#pragma unroll
        for (int c = 0; c < 10; ++c) a[c] = fmaf(b4.y, A0[16 + c], a[c]);
#pragma unroll
        for (int c = 0; c < 10; ++c) a[c] = fmaf(b4.z, A0[32 + c], a[c]);
#pragma unroll
        for (int c = 0; c < 10; ++c) a[c] = fmaf(b4.w, A0[48 + c], a[c]);
    }

    unsigned int* wp = wsorted + (size_t)pos * 5;
    wp[0] = f32_to_bf16_rne(a[0]) | (f32_to_bf16_rne(a[1]) << 16);
    wp[1] = f32_to_bf16_rne(a[2]) | (f32_to_bf16_rne(a[3]) << 16);
    wp[2] = f32_to_bf16_rne(a[4]) | (f32_to_bf16_rne(a[5]) << 16);
    wp[3] = f32_to_bf16_rne(a[6]) | (f32_to_bf16_rne(a[7]) << 16);
    wp[4] = f32_to_bf16_rne(a[8]) | (f32_to_bf16_rne(a[9]) << 16);
}

// ---------------------------------------------------------------------------
// Node scores: thread = (node, class-slot c<16); head from u01, contiguous
// bf16 w-segment sum, 16-lane-group softmax.
// ---------------------------------------------------------------------------
__global__ __launch_bounds__(256) void node_score_kernel(
    const float* __restrict__ u01,
    const int* __restrict__ off, const int* __restrict__ count,
    const unsigned int* __restrict__ w,   // [E][5] dwords, receiver-sorted
    float* __restrict__ out)
{
    const int tid = blockIdx.x * 256 + threadIdx.x;
    const int n = tid >> 4;
    const int c = tid & 15;
    if (n >= N_NODES) return;

    const int cc = (c < 10) ? c : 0;  // safe index for idle lanes
    const float s0 = u01[(size_t)n * 20 + cc];
    const float s1 = u01[(size_t)n * 20 + 10 + cc];

    const int beg = off[n];
    const int dge = count[n];
    const int end = beg + dge;
    float sc = s0 + (float)dge * s1;

    // sum bf16 w_e over this node's contiguous segment
    const int half = cc >> 1;
    const int sh = (cc & 1) * 16;
    int i = beg;
    for (; i + 3 < end; i += 4) {
        const unsigned int u0 = w[(size_t)(i + 0) * 5 + half];
        const unsigned int u1 = w[(size_t)(i + 1) * 5 + half];
        const unsigned int u2 = w[(size_t)(i + 2) * 5 + half];
        const unsigned int u3 = w[(size_t)(i + 3) * 5 + half];
        sc += __uint_as_float((u0 >> sh) << 16);
        sc += __uint_as_float((u1 >> sh) << 16);
        sc += __uint_as_float((u2 >> sh) << 16);
        sc += __uint_as_float((u3 >> sh) << 16);
    }
    for (; i < end; ++i) {
        const unsigned int u = w[(size_t)i * 5 + half];
        sc += __uint_as_float((u >> sh) << 16);
    }

    // softmax over the 10 active lanes of this 16-lane group
    float m = (c < 10) ? sc : -3.0e38f;
#pragma unroll
    for (int d = 1; d < 16; d <<= 1) m = fmaxf(m, __shfl_xor(m, d, 16));
    const float ex = (c < 10) ? __expf(sc - m) : 0.f;
    float sum = ex;
#pragma unroll
    for (int d = 1; d < 16; d <<= 1) sum += __shfl_xor(sum, d, 16);
    if (c < 10) out[(size_t)n * 10 + c] = ex / sum;
}

extern "C" void kernel_launch(void* const* d_in, const int* in_sizes, int n_in,
                              void* d_out, int out_size, void* d_ws, size_t ws_size,
                              hipStream_t stream)
{
    const float* O    = (const float*)d_in[0];
    const float* X    = (const float*)d_in[1];
    const float* R_a  = (const float*)d_in[2];
    const int* senders   = (const int*)d_in[3];
    const int* receivers = (const int*)d_in[4];
    const float* W_r  = (const float*)d_in[5];
    const float* b_r  = (const float*)d_in[6];
    const float* W_o  = (const float*)d_in[7];
    const float* b_o  = (const float*)d_in[8];
    const float* W_s  = (const float*)d_in[9];
    const float* b_s  = (const float*)d_in[10];
    float* out = (float*)d_out;
    char* ws = (char*)d_ws;

    float* A      = (float*)(ws + WS_A);
    int* count    = (int*)(ws + WS_COUNT);
    unsigned int* cursor = (unsigned int*)(ws + WS_CURSOR);
    int* off      = (int*)(ws + WS_OFF);
    int* cur      = (int*)(ws + WS_CUR);
    float* us     = (float*)(ws + WS_US);
    float* u01    = (float*)(ws + WS_U01);
    unsigned int* w = (unsigned int*)(ws + WS_W);

    // zero count histogram + cursor (adjacent) in one memset
    hipMemsetAsync(count, 0, (size_t)200004, stream);

    precompute_A<<<10, 256, 0, stream>>>(W_r, b_r, W_o, b_o, W_s, b_s, A);

    count_kernel<<<(N_EDGES / 4 + 255) / 256, 256, 0, stream>>>(receivers, count);

    alloc_kernel<<<(N_NODES + 255) / 256, 256, 0, stream>>>(count, cursor, off, cur);

    node_u_kernel<<<(N_NODES * 10 + 255) / 256, 256, 0, stream>>>(O, X, A, us, u01);

    edge_w_kernel<<<(N_EDGES + 255) / 256, 256, 0, stream>>>(
        R_a, senders, receivers, us, A, cur, w);

    node_score_kernel<<<(N_NODES * 16 + 255) / 256, 256, 0, stream>>>(
        u01, off, count, w, out);
}